// Round 1
// 1874.395 us; speedup vs baseline: 1.4453x; 1.4453x over previous
//
#include <hip/hip_runtime.h>
#include <cmath>

#define B_ 64
#define T_ 512
#define E_ 512
#define H_ 1024
#define O_ 512
#define BH (B_ * H_)
#define HSTRIDE 1160  // LDS row stride (elems)

typedef unsigned short ushort_t;
typedef __bf16 bf16x8 __attribute__((ext_vector_type(8)));
typedef float f32x4 __attribute__((ext_vector_type(4)));

__device__ __forceinline__ ushort_t f2bf(float f) {
    union { float f; unsigned int u; } x; x.f = f;
    unsigned int r = x.u + 0x7fffu + ((x.u >> 16) & 1u);
    return (ushort_t)(r >> 16);
}
__device__ __forceinline__ float bf2f(ushort_t u) {
    union { unsigned int u; float f; } x; x.u = ((unsigned int)u) << 16;
    return x.f;
}
__device__ __forceinline__ uint4 pack8bf(float4 v0, float4 v1) {
    uint4 pk;
    pk.x = (unsigned)f2bf(v0.x) | ((unsigned)f2bf(v0.y) << 16);
    pk.y = (unsigned)f2bf(v0.z) | ((unsigned)f2bf(v0.w) << 16);
    pk.z = (unsigned)f2bf(v1.x) | ((unsigned)f2bf(v1.y) << 16);
    pk.w = (unsigned)f2bf(v1.z) | ((unsigned)f2bf(v1.w) << 16);
    return pk;
}
__device__ __forceinline__ bf16x8 pack8(const float* src) {
    float4 v0 = *(const float4*)src;
    float4 v1 = *(const float4*)(src + 4);
    union { uint4 u; bf16x8 b; } c;
    c.u = pack8bf(v0, v1);
    return c.b;
}

// ---------------------------------------------------------------- prep ------
__global__ void prep_kernel(const float* __restrict__ h0, ushort_t* __restrict__ hinit,
                            int* __restrict__ bar) {
    int i = blockIdx.x * blockDim.x + threadIdx.x;
    if (i < 8192) bar[i] = 0;   // flag arrays: 2 layers x 4 groups x 32 flags x 32-int stride
    if (i < 2 * BH) hinit[i] = f2bf(h0[i]);
}

// ------------------------------------------------ big GEMM: C = A*W^T + b ---
// MODE 0: A fp32 (emb, (B,T,E), row r=t*64+b -> emb row (b,t)), out bf16 direct rows
// MODE 2: A bf16 direct rows, out fp32 remapped row r=t*64+b -> out row (b,t)
template <int MODE>
__launch_bounds__(256)
__global__ void gemm_bt(const void* __restrict__ Ap, const float* __restrict__ Wp,
                        const float* __restrict__ bias, void* __restrict__ outp,
                        int N, int K) {
    __shared__ __align__(16) ushort_t As[128 * 72];
    __shared__ __align__(16) ushort_t Bs[128 * 72];
    const int tid = threadIdx.x;
    const int lane = tid & 63;
    const int w = tid >> 6;
    const int wm = (w >> 1) * 64;
    const int wn = (w & 1) * 64;
    const int q = lane >> 4;
    const int l16 = lane & 15;
    const int m0 = blockIdx.y * 128;
    const int n0 = blockIdx.x * 128;

    const float*    Af = (const float*)Ap;
    const ushort_t* Ab = (const ushort_t*)Ap;

    f32x4 zero = {0.f, 0.f, 0.f, 0.f};
    f32x4 acc[4][4];
#pragma unroll
    for (int i = 0; i < 4; i++)
#pragma unroll
        for (int j = 0; j < 4; j++) acc[i][j] = zero;

    for (int k0 = 0; k0 < K; k0 += 64) {
#pragma unroll
        for (int it = 0; it < 4; it++) {
            int task = tid + it * 256;
            int row = task >> 3, seg = task & 7;
            if (MODE == 0) {
                int Ra = m0 + row;
                const float* src = Af + (size_t)((Ra & 63) * T_ + (Ra >> 6)) * K + k0 + seg * 8;
                float4 v0 = *(const float4*)src;
                float4 v1 = *(const float4*)(src + 4);
                *(uint4*)&As[row * 72 + seg * 8] = pack8bf(v0, v1);
            } else {
                const ushort_t* src = Ab + (size_t)(m0 + row) * K + k0 + seg * 8;
                *(uint4*)&As[row * 72 + seg * 8] = *(const uint4*)src;
            }
            const float* wsrc = Wp + (size_t)(n0 + row) * K + k0 + seg * 8;
            float4 w0 = *(const float4*)wsrc;
            float4 w1 = *(const float4*)(wsrc + 4);
            *(uint4*)&Bs[row * 72 + seg * 8] = pack8bf(w0, w1);
        }
        __syncthreads();
#pragma unroll
        for (int ks = 0; ks < 64; ks += 32) {
            bf16x8 af[4], bfr[4];
#pragma unroll
            for (int i = 0; i < 4; i++)
                af[i] = *(const bf16x8*)&As[(wm + i * 16 + l16) * 72 + ks + q * 8];
#pragma unroll
            for (int j = 0; j < 4; j++)
                bfr[j] = *(const bf16x8*)&Bs[(wn + j * 16 + l16) * 72 + ks + q * 8];
#pragma unroll
            for (int i = 0; i < 4; i++)
#pragma unroll
                for (int j = 0; j < 4; j++)
                    acc[i][j] = __builtin_amdgcn_mfma_f32_16x16x32_bf16(af[i], bfr[j], acc[i][j], 0, 0, 0);
        }
        __syncthreads();
    }

#pragma unroll
    for (int j = 0; j < 4; j++) {
        int C = n0 + wn + j * 16 + l16;
        float bv = bias[C];
#pragma unroll
        for (int i = 0; i < 4; i++) {
#pragma unroll
            for (int r = 0; r < 4; r++) {
                int R = m0 + wm + i * 16 + q * 4 + r;
                float v = acc[i][j][r] + bv;
                if (MODE == 2) {
                    ((float*)outp)[(size_t)((R & 63) * T_ + (R >> 6)) * N + C] = v;
                } else {
                    ((ushort_t*)outp)[(size_t)R * N + C] = f2bf(v);
                }
            }
        }
    }
}

// -------------------- fused two-layer persistent recurrence (1-step skew) ---
// 256 blocks x 256 threads, 1 block/CU (LDS-limited), all co-resident.
// Blocks [0,128): layer 0.  Blocks [128,256): layer 1, lagging one step.
// Block (layer, gb, cb): batch rows [16gb,+16), cols [32cb,+32).
// Flags: bar + (layer*4+gb)*1024, 32 flags @ 128B stride, monotonic.
// Layer-1 wave poll covers 64 flags: lanes 0-31 own h1 flags (>= r),
// lanes 32-63 layer-0 flags (>= r+1, i.e. x0(r) fully published).
template <int LAYER>
__device__ __forceinline__ void rnn_body(
    ushort_t* __restrict__ xall, const ushort_t* __restrict__ xsrc,
    const ushort_t* __restrict__ hin,
    const float* __restrict__ Wa, const float* __restrict__ Wb,
    const float* __restrict__ ba, const float* __restrict__ bb,
    int* __restrict__ bar,
    ushort_t* __restrict__ Hs0, ushort_t* __restrict__ Hs1,
    float (*__restrict__ Rs)[16][33]) {
    (void)xsrc;

    const int tid = threadIdx.x;
    const int lane = tid & 63;
    const int w = tid >> 6;
    const int q = lane >> 4;
    const int l16 = lane & 15;
    const int gb = (blockIdx.x >> 5) & 3;
    const int cb = blockIdx.x & 31;
    const int b0 = gb * 16;
    const int n0 = cb * 32;
    int* flags   = bar + (LAYER * 4 + gb) * 1024;  // own layer's flag group
    int* flagsrc = bar + gb * 1024;                // layer-0 flags (for LAYER 1)
    int* myflag  = flags + (cb << 5);
    int* pollp;
    int polladd;
    if (LAYER == 1) {
        pollp   = ((lane & 32) ? flagsrc : flags) + ((lane & 31) << 5);
        polladd = (lane & 32) ? 1 : 0;   // x0(r) needs producer flag r+1
    } else {
        pollp   = flags + ((lane & 31) << 5);
        polladd = 0;
    }

    // ---- register B-fragments (loop-invariant weights)
    bf16x8 wA[16], wB[16];
#pragma unroll
    for (int g = 0; g < 2; g++)
#pragma unroll
        for (int kk = 0; kk < 8; kk++) {
            size_t off = (size_t)(n0 + g * 16 + l16) * H_ + w * 256 + kk * 32 + q * 8;
            wA[g * 8 + kk] = pack8(Wa + off);
            if (LAYER == 1) wB[g * 8 + kk] = pack8(Wb + off);
        }

    const int em = tid >> 4;
    const int en = (tid & 15) * 2;
    float bv0 = ba[n0 + en], bv1 = ba[n0 + en + 1];
    if (LAYER == 1) { bv0 += bb[n0 + en]; bv1 += bb[n0 + en + 1]; }

    const int rbase2 = (tid >> 7) * 2;  // 0 or 2
    const int seg = tid & 127;

    for (int r = 0; r < 512; r++) {
        // ---- flag-array barrier wait
        if (LAYER == 1) {
            while (true) {
                int v = __hip_atomic_load(pollp, __ATOMIC_RELAXED, __HIP_MEMORY_SCOPE_SYSTEM);
                if (__ballot(v >= r + polladd) == ~0ull) break;
            }
        } else if (r > 0) {
            while (true) {
                int v = __hip_atomic_load(pollp, __ATOMIC_RELAXED, __HIP_MEMORY_SCOPE_SYSTEM);
                if (__ballot(v >= r) == ~0ull) break;
            }
        }

        // ---- stage recurrent-state rows (LLC-coherent) [+ x word / x0 tile]
        const ushort_t* s1 = (r == 0) ? hin : (xall + (size_t)(r - 1) * BH);
        const ushort_t* c0 = s1 + (size_t)(b0 + rbase2) * H_ + seg * 8;
        const ushort_t* c1 = c0 + 4 * H_;
        const ushort_t* c2 = c0 + 8 * H_;
        const ushort_t* c3 = c0 + 12 * H_;
        unsigned xw = 0;
        uint4 e0, e1, e2, e3, e4, e5, e6, e7;
        if (LAYER == 0) {
            const ushort_t* xaddr = xall + (size_t)r * BH + (size_t)(b0 + em) * H_ + n0 + en;
            asm volatile(
                "global_load_dwordx4 %0, %9, off sc0 sc1\n\t"
                "global_load_dwordx4 %1, %9, off offset:2048 sc0 sc1\n\t"
                "global_load_dwordx4 %2, %10, off sc0 sc1\n\t"
                "global_load_dwordx4 %3, %10, off offset:2048 sc0 sc1\n\t"
                "global_load_dwordx4 %4, %11, off sc0 sc1\n\t"
                "global_load_dwordx4 %5, %11, off offset:2048 sc0 sc1\n\t"
                "global_load_dwordx4 %6, %12, off sc0 sc1\n\t"
                "global_load_dwordx4 %7, %12, off offset:2048 sc0 sc1\n\t"
                "global_load_dword %8, %13, off sc0 sc1\n\t"
                "s_waitcnt vmcnt(0)"
                : "=&v"(e0), "=&v"(e1), "=&v"(e2), "=&v"(e3),
                  "=&v"(e4), "=&v"(e5), "=&v"(e6), "=&v"(e7), "=&v"(xw)
                : "v"(c0), "v"(c1), "v"(c2), "v"(c3), "v"(xaddr)
                : "memory");
        } else {
            // x0(r) produced concurrently by layer-0 blocks -> LLC-coherent load,
            // gated by the layer-0 flags polled above. Issued in the same clause
            // as the h1 loads: both drain at one vmcnt(0).
            const ushort_t* a0 = xsrc + (size_t)r * BH + (size_t)(b0 + rbase2) * H_ + seg * 8;
            const ushort_t* a1 = a0 + 4 * H_;
            const ushort_t* a2 = a0 + 8 * H_;
            const ushort_t* a3 = a0 + 12 * H_;
            uint4 d0, d1, d2, d3, d4, d5, d6, d7;
            asm volatile(
                "global_load_dwordx4 %0, %16, off sc0 sc1\n\t"
                "global_load_dwordx4 %1, %16, off offset:2048 sc0 sc1\n\t"
                "global_load_dwordx4 %2, %17, off sc0 sc1\n\t"
                "global_load_dwordx4 %3, %17, off offset:2048 sc0 sc1\n\t"
                "global_load_dwordx4 %4, %18, off sc0 sc1\n\t"
                "global_load_dwordx4 %5, %18, off offset:2048 sc0 sc1\n\t"
                "global_load_dwordx4 %6, %19, off sc0 sc1\n\t"
                "global_load_dwordx4 %7, %19, off offset:2048 sc0 sc1\n\t"
                "global_load_dwordx4 %8, %20, off sc0 sc1\n\t"
                "global_load_dwordx4 %9, %20, off offset:2048 sc0 sc1\n\t"
                "global_load_dwordx4 %10, %21, off sc0 sc1\n\t"
                "global_load_dwordx4 %11, %21, off offset:2048 sc0 sc1\n\t"
                "global_load_dwordx4 %12, %22, off sc0 sc1\n\t"
                "global_load_dwordx4 %13, %22, off offset:2048 sc0 sc1\n\t"
                "global_load_dwordx4 %14, %23, off sc0 sc1\n\t"
                "global_load_dwordx4 %15, %23, off offset:2048 sc0 sc1\n\t"
                "s_waitcnt vmcnt(0)"
                : "=&v"(d0), "=&v"(d1), "=&v"(d2), "=&v"(d3),
                  "=&v"(d4), "=&v"(d5), "=&v"(d6), "=&v"(d7),
                  "=&v"(e0), "=&v"(e1), "=&v"(e2), "=&v"(e3),
                  "=&v"(e4), "=&v"(e5), "=&v"(e6), "=&v"(e7)
                : "v"(a0), "v"(a1), "v"(a2), "v"(a3),
                  "v"(c0), "v"(c1), "v"(c2), "v"(c3)
                : "memory");
            *(uint4*)&Hs0[(rbase2 + 0) * HSTRIDE + seg * 8] = d0;
            *(uint4*)&Hs0[(rbase2 + 1) * HSTRIDE + seg * 8] = d1;
            *(uint4*)&Hs0[(rbase2 + 4) * HSTRIDE + seg * 8] = d2;
            *(uint4*)&Hs0[(rbase2 + 5) * HSTRIDE + seg * 8] = d3;
            *(uint4*)&Hs0[(rbase2 + 8) * HSTRIDE + seg * 8] = d4;
            *(uint4*)&Hs0[(rbase2 + 9) * HSTRIDE + seg * 8] = d5;
            *(uint4*)&Hs0[(rbase2 + 12) * HSTRIDE + seg * 8] = d6;
            *(uint4*)&Hs0[(rbase2 + 13) * HSTRIDE + seg * 8] = d7;
        }
        *(uint4*)&Hs1[(rbase2 + 0) * HSTRIDE + seg * 8] = e0;
        *(uint4*)&Hs1[(rbase2 + 1) * HSTRIDE + seg * 8] = e1;
        *(uint4*)&Hs1[(rbase2 + 4) * HSTRIDE + seg * 8] = e2;
        *(uint4*)&Hs1[(rbase2 + 5) * HSTRIDE + seg * 8] = e3;
        *(uint4*)&Hs1[(rbase2 + 8) * HSTRIDE + seg * 8] = e4;
        *(uint4*)&Hs1[(rbase2 + 9) * HSTRIDE + seg * 8] = e5;
        *(uint4*)&Hs1[(rbase2 + 12) * HSTRIDE + seg * 8] = e6;
        *(uint4*)&Hs1[(rbase2 + 13) * HSTRIDE + seg * 8] = e7;
        __syncthreads();

        // ---- MFMA: wave w covers K slice [256w,+256), both 16-col groups
        f32x4 acc0 = {0.f, 0.f, 0.f, 0.f};
        f32x4 acc1 = {0.f, 0.f, 0.f, 0.f};
        const int kb = w * 256;
        if (LAYER == 1) {
#pragma unroll
            for (int kk = 0; kk < 8; kk++) {
                bf16x8 a = *(const bf16x8*)&Hs0[l16 * HSTRIDE + kb + kk * 32 + q * 8];
                acc0 = __builtin_amdgcn_mfma_f32_16x16x32_bf16(a, wA[kk], acc0, 0, 0, 0);
                acc1 = __builtin_amdgcn_mfma_f32_16x16x32_bf16(a, wA[8 + kk], acc1, 0, 0, 0);
            }
#pragma unroll
            for (int kk = 0; kk < 8; kk++) {
                bf16x8 a = *(const bf16x8*)&Hs1[l16 * HSTRIDE + kb + kk * 32 + q * 8];
                acc0 = __builtin_amdgcn_mfma_f32_16x16x32_bf16(a, wB[kk], acc0, 0, 0, 0);
                acc1 = __builtin_amdgcn_mfma_f32_16x16x32_bf16(a, wB[8 + kk], acc1, 0, 0, 0);
            }
        } else {
#pragma unroll
            for (int kk = 0; kk < 8; kk++) {
                bf16x8 a = *(const bf16x8*)&Hs1[l16 * HSTRIDE + kb + kk * 32 + q * 8];
                acc0 = __builtin_amdgcn_mfma_f32_16x16x32_bf16(a, wA[kk], acc0, 0, 0, 0);
                acc1 = __builtin_amdgcn_mfma_f32_16x16x32_bf16(a, wA[8 + kk], acc1, 0, 0, 0);
            }
        }
#pragma unroll
        for (int rr = 0; rr < 4; rr++) {
            Rs[w][q * 4 + rr][l16] = acc0[rr];
            Rs[w][q * 4 + rr][16 + l16] = acc1[rr];
        }
        __syncthreads();

        // ---- reduce 4 waves + tanh + coherent store of a col pair
        {
            float sA = Rs[0][em][en] + Rs[1][em][en] + Rs[2][em][en] + Rs[3][em][en];
            float sB = Rs[0][em][en + 1] + Rs[1][em][en + 1] + Rs[2][em][en + 1] + Rs[3][em][en + 1];
            ushort_t* dst = xall + (size_t)r * BH + (size_t)(b0 + em) * H_ + n0 + en;
            if (LAYER == 0) {
                sA += bf2f((ushort_t)(xw & 0xffff));
                sB += bf2f((ushort_t)(xw >> 16));
            }
            sA += bv0;
            sB += bv1;
            unsigned pk = (unsigned)f2bf(tanhf(sA)) | ((unsigned)f2bf(tanhf(sB)) << 16);
            __hip_atomic_store((unsigned*)dst, pk, __ATOMIC_RELAXED, __HIP_MEMORY_SCOPE_SYSTEM);
        }

        // ---- signal: drain stores, then publish this block's flag.
        // Layer 0 must publish r=511 too (layer 1 consumes x0(511)).
        if (LAYER == 0 || r < 511) {
            __syncthreads();  // vmcnt(0) drain: h stores LLC-visible before flag
            if (tid == 0)
                __hip_atomic_store(myflag, r + 1, __ATOMIC_RELAXED, __HIP_MEMORY_SCOPE_SYSTEM);
        }
    }
}

__launch_bounds__(256, 1)
__global__ void rnn_fused(ushort_t* __restrict__ x0, ushort_t* __restrict__ x1,
                          const ushort_t* __restrict__ hinit,
                          const float* __restrict__ W_hh0, const float* __restrict__ b_hh0,
                          const float* __restrict__ W_ih1, const float* __restrict__ W_hh1,
                          const float* __restrict__ b_ih1, const float* __restrict__ b_hh1,
                          int* __restrict__ bar) {
    __shared__ __align__(16) ushort_t Hs0[16 * HSTRIDE];  // x-source rows (layer 1)
    __shared__ __align__(16) ushort_t Hs1[16 * HSTRIDE];  // recurrent-state rows
    __shared__ float Rs[4][16][33];
    if (blockIdx.x < 128) {
        rnn_body<0>(x0, (const ushort_t*)nullptr, hinit,
                    W_hh0, W_hh0, b_hh0, b_hh0, bar, Hs0, Hs1, Rs);
    } else {
        rnn_body<1>(x1, x0, hinit + BH,
                    W_ih1, W_hh1, b_ih1, b_hh1, bar, Hs0, Hs1, Rs);
    }
}

// ---------------------------------------------------------------- launch ----
extern "C" void kernel_launch(void* const* d_in, const int* in_sizes, int n_in,
                              void* d_out, int out_size, void* d_ws, size_t ws_size,
                              hipStream_t stream) {
    (void)in_sizes; (void)n_in; (void)out_size; (void)ws_size;
    const float* emb   = (const float*)d_in[0];
    const float* h0    = (const float*)d_in[1];
    const float* W_ih0 = (const float*)d_in[2];
    const float* b_ih0 = (const float*)d_in[3];
    const float* W_ih1 = (const float*)d_in[4];
    const float* b_ih1 = (const float*)d_in[5];
    const float* W_hh0 = (const float*)d_in[6];
    const float* b_hh0 = (const float*)d_in[7];
    const float* W_hh1 = (const float*)d_in[8];
    const float* b_hh1 = (const float*)d_in[9];
    const float* W_out = (const float*)d_in[10];
    const float* b_out = (const float*)d_in[11];
    float* out = (float*)d_out;

    char* ws = (char*)d_ws;
    int*      bar   = (int*)ws;                      // flag arrays (8192 ints)
    ushort_t* hinit = (ushort_t*)(ws + 65536);       // 2*B*H bf16
    ushort_t* xp    = (ushort_t*)(ws + 65536 + 2 * BH * 2);  // (T,B,H) bf16: x0 -> h0
    ushort_t* xq    = xp + (size_t)T_ * BH;                  // (T,B,H) bf16: h1

    prep_kernel<<<512, 256, 0, stream>>>(h0, hinit, bar);

    // xp = emb . W_ih0^T + b_ih0   (stored (T,B,H))
    gemm_bt<0><<<dim3(H_ / 128, (B_ * T_) / 128), 256, 0, stream>>>(
        emb, W_ih0, b_ih0, xp, H_, E_);

    // fused: layer 0 (xp := h0_all in place) || layer 1 (xq := h1_all),
    // layer 1 lags one step, consuming x0(r) via layer-0 flags
    rnn_fused<<<256, 256, 0, stream>>>(xp, xq, hinit,
                                       W_hh0, b_hh0, W_ih1, W_hh1, b_ih1, b_hh1, bar);

    // out = h1_all . W_out^T + b_out   ((B,T,O) fp32)
    gemm_bt<2><<<dim3(O_ / 128, (B_ * T_) / 128), 256, 0, stream>>>(
        xq, W_out, b_out, out, O_, H_);
}